// Round 8
// baseline (159.801 us; speedup 1.0000x reference)
//
#include <hip/hip_runtime.h>
#include <stdint.h>

#define NTOK 4096
#define HDIM 1024
#define DDIM 2048
#define NEXP 8
#define NASS 8192   // NTOK * K (K=2)

typedef __attribute__((ext_vector_type(8))) short bf16x8;
typedef __attribute__((ext_vector_type(4))) float f32x4;

typedef __attribute__((address_space(1))) const unsigned int gu32;
typedef __attribute__((address_space(3))) unsigned int lu32;

// barrier that is ALSO a compiler memory fence (raw builtin is not; R5 raced)
#define BARRIER() asm volatile("s_barrier" ::: "memory")
#define WAIT_VM0() asm volatile("s_waitcnt vmcnt(0)" ::: "memory")

__device__ __forceinline__ void async16(void* lds, const void* g) {
  __builtin_amdgcn_global_load_lds((gu32*)(uintptr_t)g, (lu32*)(uintptr_t)lds, 16, 0, 0);
}

__device__ __forceinline__ unsigned short f2bf(float f) {
  unsigned int u = __float_as_uint(f);
  return (unsigned short)((u + 0x7fffu + ((u >> 16) & 1u)) >> 16);
}
__device__ __forceinline__ float bf2f(unsigned short u) {
  return __uint_as_float(((unsigned int)u) << 16);
}

// ---------------- x fp32 -> bf16 ----------------
__global__ __launch_bounds__(256) void k_cvt_x(const float* __restrict__ x,
                                               unsigned short* __restrict__ x16) {
  int i = blockIdx.x * 256 + threadIdx.x;
  float4 v = reinterpret_cast<const float4*>(x)[i];
  ushort4 o;
  o.x = f2bf(v.x); o.y = f2bf(v.y); o.z = f2bf(v.z); o.w = f2bf(v.w);
  reinterpret_cast<ushort4*>(x16)[i] = o;
}

// ---------------- [E][R][C] fp32 -> [E][C][R] bf16 (tiled transpose) ----------------
__global__ __launch_bounds__(256) void k_transpose(const float* __restrict__ in,
                                                   unsigned short* __restrict__ out,
                                                   int R, int C) {
  __shared__ float t[32][33];
  const size_t mbase = (size_t)blockIdx.z * R * C;
  int tid = threadIdx.x;
  int r = tid >> 3, c4 = (tid & 7) * 4;
  int gr = blockIdx.y * 32 + r;
  int gc = blockIdx.x * 32 + c4;
  float4 v = *reinterpret_cast<const float4*>(in + mbase + (size_t)gr * C + gc);
  t[r][c4 + 0] = v.x; t[r][c4 + 1] = v.y; t[r][c4 + 2] = v.z; t[r][c4 + 3] = v.w;
  __syncthreads();
  int orow = blockIdx.x * 32 + r;    // original col
  int oc4  = blockIdx.y * 32 + c4;   // original row
  ushort4 o;
  o.x = f2bf(t[c4 + 0][r]); o.y = f2bf(t[c4 + 1][r]);
  o.z = f2bf(t[c4 + 2][r]); o.w = f2bf(t[c4 + 3][r]);
  *reinterpret_cast<ushort4*>(out + mbase + (size_t)orow * R + oc4) = o;
}

// ---------------- routing: detect+count+scan+scatter in ONE block ----------------
__global__ __launch_bounds__(1024) void k_route(
    const int* __restrict__ idx, const float* __restrict__ ew,
    const int* __restrict__ amask,
    int* __restrict__ counts_g, int* __restrict__ offs_g,
    int* __restrict__ toks, float* __restrict__ wl, int* __restrict__ slotmap) {
  __shared__ int cnt[NEXP], cur[NEXP], flag;
  const int t = threadIdx.x;
  if (t < NEXP) cnt[t] = 0;
  if (t == 0) flag = 0;
  __syncthreads();
  // dtype detect: if int64, all high (odd) words are 0
  int lf = 0;
#pragma unroll
  for (int j = 0; j < 4; ++j) {
    int i = t + j * 1024;
    if (idx[2 * i + 1] != 0) lf = 1;
  }
  if (lf) atomicOr(&flag, 1);
  __syncthreads();
  const int is32 = flag;
  int e[8];
#pragma unroll
  for (int j = 0; j < 8; ++j) {
    int i = t + j * 1024;
    int ei = is32 ? idx[i] : idx[2 * i];
    e[j] = ei;
    atomicAdd(&cnt[ei], 1);
  }
  __syncthreads();
  if (t == 0) {
    int off = 0;
    for (int k = 0; k < NEXP; ++k) {
      cur[k] = off; offs_g[k] = off; counts_g[k] = cnt[k]; off += cnt[k];
    }
  }
  __syncthreads();
#pragma unroll
  for (int j = 0; j < 8; ++j) {
    int i = t + j * 1024;
    int n = i >> 1;
    int slot = atomicAdd(&cur[e[j]], 1);
    toks[slot] = n;
    wl[slot] = ew[i] * (amask[n] ? 1.0f : 0.0f);
    slotmap[i] = slot;
  }
}

// ---------------- fused: grouped GEMM1 (hid = relu(X[gather] @ down)) + transpose(up) ----------
// blockIdx.x == XCD == expert (round-robin dispatch). y<1024: GEMM tile; y>=1024: transpose role.
// GEMM: 512 threads, 8 waves (2Mx4N, each 64x32), 128x128 tile, BK=64, dbuf,
// SINGLE barrier + single vmcnt(0) per K-tile; compiler schedules lgkmcnt.
__global__ __launch_bounds__(512, 4) void k_down_fused(
    const unsigned short* __restrict__ x16, const unsigned short* __restrict__ bT,
    const int* __restrict__ counts, const int* __restrict__ offs,
    const int* __restrict__ toks, unsigned short* __restrict__ hid,
    const float* __restrict__ up, unsigned short* __restrict__ upT) {
  const int e = blockIdx.x;                 // expert == XCD
  const int q = blockIdx.y;
  const int tid = threadIdx.x;
  __shared__ alignas(16) char lds[65536];   // GEMM: A dbuf @0, B dbuf @32768. Transpose aliases.

  if (q >= 1024) {
    // ---- transpose role: up[e] fp32 [DDIM][HDIM] -> upT[e] [HDIM][DDIM] bf16 ----
    // 2 tiles of 32x32 per block (one per 256-thread group)
    const int tt = (q - 1024) * 2 + (tid >> 8);   // 0..2047
    const int bx = tt & 31;                       // HDIM/32
    const int by = tt >> 5;                       // DDIM/32
    float* tb = (float*)lds + (tid >> 8) * (32 * 33);
    const int t2 = tid & 255;
    const int r = t2 >> 3, c4 = (t2 & 7) * 4;
    const size_t mbase = (size_t)e * DDIM * HDIM;
    const int gr = by * 32 + r;     // D row
    const int gc = bx * 32 + c4;    // H col
    float4 v = *reinterpret_cast<const float4*>(up + mbase + (size_t)gr * HDIM + gc);
    tb[r * 33 + c4 + 0] = v.x; tb[r * 33 + c4 + 1] = v.y;
    tb[r * 33 + c4 + 2] = v.z; tb[r * 33 + c4 + 3] = v.w;
    __syncthreads();
    const int orow = bx * 32 + r;   // H row
    const int oc4  = by * 32 + c4;  // D col
    ushort4 o;
    o.x = f2bf(tb[(c4 + 0) * 33 + r]); o.y = f2bf(tb[(c4 + 1) * 33 + r]);
    o.z = f2bf(tb[(c4 + 2) * 33 + r]); o.w = f2bf(tb[(c4 + 3) * 33 + r]);
    *reinterpret_cast<ushort4*>(upT + mbase + (size_t)orow * DDIM + oc4) = o;
    return;
  }

  // ---- GEMM role ----
  const int cnt = counts[e];
  const int mt = q >> 4;                    // 0..63 capacity
  const int nt = q & 15;                    // 0..15
  if (mt * 128 >= cnt) return;
  const int base = offs[e];
  const int lane = tid & 63;
  const int wr = ((tid >> 8) & 1) * 64;     // wave row block (2)
  const int wc = ((tid >> 6) & 3) * 32;     // wave col block (4)

  // staging: LDS linear [128 rows][128B]; global col pre-swizzled so
  // LDS[row][c] = G[row][c ^ ((row&7)<<4)]   (rule #21)
  const char* gA[2]; const char* gB[2]; int sOff[2];
  {
    const int swcol = ((tid & 7) << 4) ^ (((tid >> 3) & 7) << 4);
#pragma unroll
    for (int it = 0; it < 2; ++it) {
      int row = it * 64 + (tid >> 3);
      int sl = mt * 128 + row; if (sl >= cnt) sl = cnt - 1;
      gA[it] = (const char*)(x16 + (size_t)toks[base + sl] * HDIM) + swcol;
      gB[it] = (const char*)(bT + (size_t)e * DDIM * HDIM + (size_t)(nt * 128 + row) * HDIM) + swcol;
      sOff[it] = it * 8192 + tid * 16;
    }
  }
  const int swz = (lane & 7) << 4;
  const int lo = (lane >> 4) << 4;
  int rowA[4], rowB[2];
#pragma unroll
  for (int m = 0; m < 4; ++m) rowA[m] = (wr + m * 16 + (lane & 15)) * 128;
#pragma unroll
  for (int n = 0; n < 2; ++n) rowB[n] = (wc + n * 16 + (lane & 15)) * 128;

  // prologue: stage K-tile 0 into buf0
#pragma unroll
  for (int it = 0; it < 2; ++it) {
    async16(lds + sOff[it], gA[it]);
    async16(lds + 32768 + sOff[it], gB[it]);
  }
  WAIT_VM0();
  BARRIER();

  f32x4 acc[4][2] = {};
  for (int j = 0; j < 16; ++j) {
    char* curA = lds + ((j & 1) << 14);
    char* curB = lds + 32768 + ((j & 1) << 14);
    char* nxtA = lds + ((~j & 1) << 14);
    char* nxtB = lds + 32768 + ((~j & 1) << 14);
    bf16x8 fa0[4], fb0[2], fa1[4], fb1[2];
    {
      const int cx = lo ^ swz;
#pragma unroll
      for (int m = 0; m < 4; ++m) fa0[m] = *reinterpret_cast<const bf16x8*>(curA + rowA[m] + cx);
#pragma unroll
      for (int n = 0; n < 2; ++n) fb0[n] = *reinterpret_cast<const bf16x8*>(curB + rowB[n] + cx);
    }
    if (j < 15) {
      const int ko = (j + 1) << 7;   // +128 bytes per K-tile
#pragma unroll
      for (int it = 0; it < 2; ++it) {
        async16(nxtA + sOff[it], gA[it] + ko);
        async16(nxtB + sOff[it], gB[it] + ko);
      }
    }
    {
      const int cx = (64 | lo) ^ swz;
#pragma unroll
      for (int m = 0; m < 4; ++m) fa1[m] = *reinterpret_cast<const bf16x8*>(curA + rowA[m] + cx);
#pragma unroll
      for (int n = 0; n < 2; ++n) fb1[n] = *reinterpret_cast<const bf16x8*>(curB + rowB[n] + cx);
    }
#pragma unroll
    for (int m = 0; m < 4; ++m)
#pragma unroll
      for (int n = 0; n < 2; ++n)
        acc[m][n] = __builtin_amdgcn_mfma_f32_16x16x32_bf16(fa0[m], fb0[n], acc[m][n], 0, 0, 0);
#pragma unroll
    for (int m = 0; m < 4; ++m)
#pragma unroll
      for (int n = 0; n < 2; ++n)
        acc[m][n] = __builtin_amdgcn_mfma_f32_16x16x32_bf16(fa1[m], fb1[n], acc[m][n], 0, 0, 0);
    WAIT_VM0();      // this tile's prefetch landed (issued ~16 MFMA earlier)
    BARRIER();       // all waves' reads of cur done; nxt fully staged
  }

#pragma unroll
  for (int m = 0; m < 4; ++m) {
    int r0 = mt * 128 + wr + m * 16 + ((lane >> 4) * 4);
#pragma unroll
    for (int j = 0; j < 4; ++j) {
      int r = r0 + j;
      if (r < cnt) {
        unsigned short* dst = hid + (size_t)(base + r) * DDIM + nt * 128 + wc + (lane & 15);
#pragma unroll
        for (int n = 0; n < 2; ++n) {
          float v = acc[m][n][j];
          dst[n * 16] = f2bf(v > 0.f ? v : 0.f);
        }
      }
    }
  }
}

// ---------------- grouped GEMM2: yw[slot] = hid[slot] @ up  (K=2048) ----------------
// Expert->XCD colocation; single-barrier K-loop (as above).
__global__ __launch_bounds__(512, 4) void k_gemm_up(
    const unsigned short* __restrict__ hid, const unsigned short* __restrict__ bT,
    const int* __restrict__ counts, const int* __restrict__ offs,
    unsigned short* __restrict__ yw) {
  const int e = blockIdx.x;                 // expert == XCD
  const int cnt = counts[e];
  const int q = blockIdx.y;
  const int mt = q >> 3;                    // 0..63 capacity
  const int nt = q & 7;                     // 0..7
  if (mt * 128 >= cnt) return;
  const int base = offs[e];
  __shared__ alignas(16) char lds[65536];
  const int tid = threadIdx.x;
  const int lane = tid & 63;
  const int wr = ((tid >> 8) & 1) * 64;
  const int wc = ((tid >> 6) & 3) * 32;

  const char* gA[2]; const char* gB[2]; int sOff[2];
  {
    const int swcol = ((tid & 7) << 4) ^ (((tid >> 3) & 7) << 4);
#pragma unroll
    for (int it = 0; it < 2; ++it) {
      int row = it * 64 + (tid >> 3);
      int sl = mt * 128 + row; if (sl >= cnt) sl = cnt - 1;
      gA[it] = (const char*)(hid + (size_t)(base + sl) * DDIM) + swcol;
      gB[it] = (const char*)(bT + (size_t)e * HDIM * DDIM + (size_t)(nt * 128 + row) * DDIM) + swcol;
      sOff[it] = it * 8192 + tid * 16;
    }
  }
  const int swz = (lane & 7) << 4;
  const int lo = (lane >> 4) << 4;
  int rowA[4], rowB[2];
#pragma unroll
  for (int m = 0; m < 4; ++m) rowA[m] = (wr + m * 16 + (lane & 15)) * 128;
#pragma unroll
  for (int n = 0; n < 2; ++n) rowB[n] = (wc + n * 16 + (lane & 15)) * 128;

#pragma unroll
  for (int it = 0; it < 2; ++it) {
    async16(lds + sOff[it], gA[it]);
    async16(lds + 32768 + sOff[it], gB[it]);
  }
  WAIT_VM0();
  BARRIER();

  f32x4 acc[4][2] = {};
  for (int j = 0; j < 32; ++j) {
    char* curA = lds + ((j & 1) << 14);
    char* curB = lds + 32768 + ((j & 1) << 14);
    char* nxtA = lds + ((~j & 1) << 14);
    char* nxtB = lds + 32768 + ((~j & 1) << 14);
    bf16x8 fa0[4], fb0[2], fa1[4], fb1[2];
    {
      const int cx = lo ^ swz;
#pragma unroll
      for (int m = 0; m < 4; ++m) fa0[m] = *reinterpret_cast<const bf16x8*>(curA + rowA[m] + cx);
#pragma unroll
      for (int n = 0; n < 2; ++n) fb0[n] = *reinterpret_cast<const bf16x8*>(curB + rowB[n] + cx);
    }
    if (j < 31) {
      const int ko = (j + 1) << 7;
#pragma unroll
      for (int it = 0; it < 2; ++it) {
        async16(nxtA + sOff[it], gA[it] + ko);
        async16(nxtB + sOff[it], gB[it] + ko);
      }
    }
    {
      const int cx = (64 | lo) ^ swz;
#pragma unroll
      for (int m = 0; m < 4; ++m) fa1[m] = *reinterpret_cast<const bf16x8*>(curA + rowA[m] + cx);
#pragma unroll
      for (int n = 0; n < 2; ++n) fb1[n] = *reinterpret_cast<const bf16x8*>(curB + rowB[n] + cx);
    }
#pragma unroll
    for (int m = 0; m < 4; ++m)
#pragma unroll
      for (int n = 0; n < 2; ++n)
        acc[m][n] = __builtin_amdgcn_mfma_f32_16x16x32_bf16(fa0[m], fb0[n], acc[m][n], 0, 0, 0);
#pragma unroll
    for (int m = 0; m < 4; ++m)
#pragma unroll
      for (int n = 0; n < 2; ++n)
        acc[m][n] = __builtin_amdgcn_mfma_f32_16x16x32_bf16(fa1[m], fb1[n], acc[m][n], 0, 0, 0);
    WAIT_VM0();
    BARRIER();
  }

#pragma unroll
  for (int m = 0; m < 4; ++m) {
    int r0 = mt * 128 + wr + m * 16 + ((lane >> 4) * 4);
#pragma unroll
    for (int j = 0; j < 4; ++j) {
      int r = r0 + j;
      if (r < cnt) {
        unsigned short* dst = yw + (size_t)(base + r) * HDIM + nt * 128 + wc + (lane & 15);
#pragma unroll
        for (int n = 0; n < 2; ++n) dst[n * 16] = f2bf(acc[m][n][j]);
      }
    }
  }
}

// ---------------- combine: out = x + w0*y0 + w1*y1 ----------------
__global__ __launch_bounds__(256) void k_combine(
    const float* __restrict__ x, const unsigned short* __restrict__ yw,
    const int* __restrict__ slotmap, const float* __restrict__ wl,
    float* __restrict__ out) {
  const int n = blockIdx.x;
  const int t = threadIdx.x;
  const int s0 = slotmap[2 * n], s1 = slotmap[2 * n + 1];
  const float w0 = wl[s0], w1 = wl[s1];
  float4 xv = reinterpret_cast<const float4*>(x + (size_t)n * HDIM)[t];
  ushort4 a0 = reinterpret_cast<const ushort4*>(yw + (size_t)s0 * HDIM)[t];
  ushort4 b0 = reinterpret_cast<const ushort4*>(yw + (size_t)s1 * HDIM)[t];
  float4 r;
  r.x = xv.x + w0 * bf2f(a0.x) + w1 * bf2f(b0.x);
  r.y = xv.y + w0 * bf2f(a0.y) + w1 * bf2f(b0.y);
  r.z = xv.z + w0 * bf2f(a0.z) + w1 * bf2f(b0.z);
  r.w = xv.w + w0 * bf2f(a0.w) + w1 * bf2f(b0.w);
  reinterpret_cast<float4*>(out + (size_t)n * HDIM)[t] = r;
}

extern "C" void kernel_launch(void* const* d_in, const int* in_sizes, int n_in,
                              void* d_out, int out_size, void* d_ws, size_t ws_size,
                              hipStream_t stream) {
  const float* x    = (const float*)d_in[0];
  const int* amask  = (const int*)d_in[1];
  const float* ew   = (const float*)d_in[2];
  const int* cidx   = (const int*)d_in[3];
  const float* dn   = (const float*)d_in[4];
  const float* up   = (const float*)d_in[5];
  float* out        = (float*)d_out;
  char* ws          = (char*)d_ws;

  const size_t X16_OFF = 0;
  const size_t DNT_OFF = X16_OFF + (size_t)NTOK * HDIM * 2;             // 8.4MB
  const size_t UPT_OFF = DNT_OFF + (size_t)NEXP * HDIM * DDIM * 2;      // +33.5MB
  const size_t HID_OFF = UPT_OFF + (size_t)NEXP * HDIM * DDIM * 2;      // +33.5MB
  const size_t MET_OFF = HID_OFF + (size_t)NASS * DDIM * 2;             // +33.5MB

  unsigned short* x16 = (unsigned short*)(ws + X16_OFF);
  unsigned short* dnT = (unsigned short*)(ws + DNT_OFF);
  unsigned short* upT = (unsigned short*)(ws + UPT_OFF);
  unsigned short* hid = (unsigned short*)(ws + HID_OFF);
  // yw ([NASS][HDIM] bf16, 16.8MB) aliases dnT: dnT dead after k_down_fused
  unsigned short* yw  = (unsigned short*)(ws + DNT_OFF);
  int* counts  = (int*)(ws + MET_OFF);
  int* offs    = counts + 8;
  int* toks    = counts + 32;
  float* wl    = (float*)(toks + NASS);
  int* slotmap = (int*)(wl + NASS);

  k_cvt_x<<<NTOK * HDIM / 1024, 256, 0, stream>>>(x, x16);
  k_transpose<<<dim3(DDIM / 32, HDIM / 32, NEXP), 256, 0, stream>>>(dn, dnT, HDIM, DDIM);
  k_route<<<1, 1024, 0, stream>>>(cidx, ew, amask, counts, offs, toks, wl, slotmap);
  // blockIdx.x == XCD id (round-robin dispatch) == expert id.
  // y<1024: GEMM1 tiles; y>=1024: transpose(up) hidden under the GEMM.
  k_down_fused<<<dim3(8, 2048), 512, 0, stream>>>(x16, dnT, counts, offs, toks, hid,
                                                  up, upT);
  k_gemm_up<<<dim3(8, 512), 512, 0, stream>>>(hid, upT, counts, offs, yw);
  k_combine<<<NTOK, 256, 0, stream>>>(x, yw, slotmap, wl, out);
}